// Round 8
// baseline (159.921 us; speedup 1.0000x reference)
//
#include <hip/hip_runtime.h>
#include <hip/hip_bf16.h>

#define S_LEN 4096
#define D_DIM 64
#define NBATCH 4
#define OPSLOT 8192   // u16 per slot: 128 rows * 64 cols
#define NSLOT 528     // 2-tile chunks per batch: sum_{b=0}^{31} (32-b) = 528

typedef unsigned short u16;
typedef unsigned int u32;
typedef __attribute__((ext_vector_type(8))) __bf16 bf16x8;
typedef __attribute__((ext_vector_type(4))) float f32x4;
typedef __attribute__((ext_vector_type(16))) float f32x16;

__device__ __forceinline__ u16 f_to_bf16u(float f) {
    union { float f; u32 u; } x; x.f = f;
    u32 r = x.u + 0x7fffu + ((x.u >> 16) & 1u);   // RNE; inputs finite
    return (u16)(r >> 16);
}

__device__ __forceinline__ u32 pack_bf16_2(float a, float b) {
    union { __hip_bfloat162 h; u32 u; } z;
    z.h = __float22bfloat162_rn(float2{a, b});
    return z.u;
}

// ---------------------------------------------------------------------------
// QKV projection. Q PRE-SCALED by 0.125*log2(e).
// Q/K written FRAGMENT-MAJOR: Xf[(b*128+blk32)*4 + c2][lane][8] with
//   element = X[blk32*32 + (lane&31)][c2*16 + (lane>>5)*8 + e]
// V written fragment-major for the PV B-operand:
//   Vf[((b*64+jt)*4 + c2)*2 + dblk][lane][8]
//   element = V[s = jt*64 + c2*16 + (lane>>5)*8 + e][d = dblk*32 + (lane&31)]
// -> every flash fragment load is one fully-coalesced dwordx4 (1 KB/wave).
// ---------------------------------------------------------------------------
__global__ __launch_bounds__(256, 2)
void proj_qkv_kernel(const float* __restrict__ q, const float* __restrict__ k,
                     const float* __restrict__ v,
                     const float* __restrict__ Wq, const float* __restrict__ bq,
                     const float* __restrict__ Wk, const float* __restrict__ bk,
                     const float* __restrict__ Wv, const float* __restrict__ bv,
                     u16* __restrict__ Qf, u16* __restrict__ Kf, u16* __restrict__ Vf)
{
    __shared__ __align__(16) u16 vt[64 * 72];

    const int p = blockIdx.y;
    const float* inp  = (p == 0) ? q  : (p == 1) ? k  : v;
    const float* W    = (p == 0) ? Wq : (p == 1) ? Wk : Wv;
    const float* bias = (p == 0) ? bq : (p == 1) ? bk : bv;
    const float scl   = (p == 0) ? 0.18033688011112042f : 1.0f;

    const int tid  = threadIdx.x;
    const int wid  = tid >> 6;
    const int lane = tid & 63;
    const int ln   = lane & 15;
    const int qd   = lane >> 4;
    const int row0 = blockIdx.x * 64;
    const int r0w  = row0 + wid * 16;

    bf16x8 afrag[2];
#pragma unroll
    for (int c = 0; c < 2; ++c) {
        const float* src = inp + (r0w + ln) * 64 + c * 32 + qd * 8;
        float4 f0 = *(const float4*)src;
        float4 f1 = *(const float4*)(src + 4);
        bf16x8 a;
        a[0] = (__bf16)f0.x; a[1] = (__bf16)f0.y; a[2] = (__bf16)f0.z; a[3] = (__bf16)f0.w;
        a[4] = (__bf16)f1.x; a[5] = (__bf16)f1.y; a[6] = (__bf16)f1.z; a[7] = (__bf16)f1.w;
        afrag[c] = a;
    }

    bf16x8 bfrag[4][2];
    float  bcol[4];
#pragma unroll
    for (int nb = 0; nb < 4; ++nb) {
        bcol[nb] = bias[nb * 16 + ln];
#pragma unroll
        for (int c = 0; c < 2; ++c) {
            const float* src = W + (nb * 16 + ln) * 64 + c * 32 + qd * 8;
            float4 f0 = *(const float4*)src;
            float4 f1 = *(const float4*)(src + 4);
            bf16x8 b;
            b[0] = (__bf16)f0.x; b[1] = (__bf16)f0.y; b[2] = (__bf16)f0.z; b[3] = (__bf16)f0.w;
            b[4] = (__bf16)f1.x; b[5] = (__bf16)f1.y; b[6] = (__bf16)f1.z; b[7] = (__bf16)f1.w;
            bfrag[nb][c] = b;
        }
    }

    f32x4 acc[4];
#pragma unroll
    for (int nb = 0; nb < 4; ++nb) acc[nb] = (f32x4){0.f, 0.f, 0.f, 0.f};
#pragma unroll
    for (int c = 0; c < 2; ++c)
#pragma unroll
        for (int nb = 0; nb < 4; ++nb)
            acc[nb] = __builtin_amdgcn_mfma_f32_16x16x32_bf16(afrag[c], bfrag[nb][c], acc[nb], 0, 0, 0);

    if (p < 2) {
        u16* dst = (p == 0) ? Qf : Kf;
#pragma unroll
        for (int nb = 0; nb < 4; ++nb)
#pragma unroll
            for (int r = 0; r < 4; ++r) {
                const int rowg = r0w + qd * 4 + r;
                const int bb   = rowg >> 12;
                const int ri   = rowg & 4095;
                const int addr = ((bb * 128 + (ri >> 5)) * 4 + nb) * 512
                               + ((ln >> 3) * 32 + (ri & 31)) * 8 + (ln & 7);
                dst[addr] = f_to_bf16u((acc[nb][r] + bcol[nb]) * scl);
            }
    } else {
#pragma unroll
        for (int nb = 0; nb < 4; ++nb)
#pragma unroll
            for (int r = 0; r < 4; ++r)
                vt[(wid * 16 + qd * 4 + r) * 72 + nb * 16 + ln] = f_to_bf16u(acc[nb][r] + bcol[nb]);
        __syncthreads();
        // fragment-major V: thread t -> (c2 = t>>6, lane = t&63), dblk 0..1
        const int c2w  = tid >> 6;
        const int lw   = tid & 63;
        const int lhw  = lw >> 5;
        const int l31w = lw & 31;
        const int bb   = row0 >> 12;
        const int jt   = (row0 & 4095) >> 6;
        u16* vdst = Vf + ((size_t)((bb * 64 + jt) * 4 + c2w) * 2) * 512 + lw * 8;
        __align__(16) u16 t8[8];
#pragma unroll
        for (int dblk = 0; dblk < 2; ++dblk) {
#pragma unroll
            for (int e = 0; e < 8; ++e)
                t8[e] = vt[(c2w * 16 + lhw * 8 + e) * 72 + dblk * 32 + l31w];
            *(uint4*)(vdst + dblk * 512) = *(const uint4*)t8;
        }
    }
}

// ---------------------------------------------------------------------------
// Flash v12: no LDS/barriers, fragment-major coalesced loads (v11), but
// 2-TILE chunks: band b has 64-2b = 2*(32-b) tiles, NC(b)=32-b chunks ->
// EVERY block exactly 2 tiles, zero empties. Grid = 4 x 528 = 2112 blocks
// (~8/CU); launch_bounds(256,6) caps VGPR ~84 (natural 64, no spill) ->
// ~24+ waves/CU vs v10's 16: latency-hiding for the 75%-stall measured in
// round 5 (VALUBusy 22%, Occ 25%). Cb(b) = 32b - b(b-1)/2.
// ---------------------------------------------------------------------------
__global__ __launch_bounds__(256, 6)
void flash_kernel(const u16* __restrict__ Qf, const u16* __restrict__ Kf,
                  const u16* __restrict__ Vf, u16* __restrict__ Op,
                  float* __restrict__ Lp)
{
    const int tid  = threadIdx.x;
    const int wid  = tid >> 6;
    const int lane = tid & 63;
    const int l31  = lane & 31;
    const int lh   = lane >> 5;

    const int bid   = blockIdx.x;
    const int batch = bid & 3;            // XCD locality
    const int qc    = bid >> 2;           // per-batch chunk id 0..527

    int band = 0;
    while (qc >= 32 * (band + 1) - (((band + 1) * band) >> 1)) ++band;
    const int NC = 32 - band;
    const int Cb = 32 * band - ((band * (band - 1)) >> 1);
    const int ch = qc - Cb;

    const int i0w = band * 128 + wid * 32;

    // Q fragments: one coalesced dwordx4 per c2
    bf16x8 qf[4];
    {
        const u16* qb = Qf + ((size_t)((batch * 128 + band * 4 + wid) * 4)) * 512 + lane * 8;
#pragma unroll
        for (int c2 = 0; c2 < 4; ++c2)
            qf[c2] = *(const bf16x8*)(qb + c2 * 512);
    }

    const u16* kfb = Kf + ((size_t)batch * 128 * 4) * 512 + lane * 8;
    const u16* vfb = Vf + ((size_t)batch * 64 * 8) * 512 + lane * 8;

    f32x16 o0, o1;
#pragma unroll
    for (int r = 0; r < 16; ++r) { o0[r] = 0.f; o1[r] = 0.f; }
    float lsum = 0.f;

#pragma unroll 1
    for (int jt = 2 * band + ch; jt < 64; jt += NC) {
        const int j0 = jt * 64;
        const bool needmask = (j0 < i0w + 32);
        const int qr = i0w + l31 - j0;    // local qrow bound

#pragma unroll
        for (int mi = 0; mi < 2; ++mi) {
            const u16* kt = kfb + (size_t)(jt * 2 + mi) * 2048;

            // ---- S^T (kcols mi*32..mi*32+31)
            f32x16 s;
#pragma unroll
            for (int r = 0; r < 16; ++r) s[r] = 0.f;
#pragma unroll
            for (int c2 = 0; c2 < 4; ++c2) {
                bf16x8 a = *(const bf16x8*)(kt + c2 * 512);
                s = __builtin_amdgcn_mfma_f32_32x32x16_bf16(a, qf[c2], s, 0, 0, 0);
            }

            // ---- exp2 (Q pre-scaled) + mask; per-lane l partial
#pragma unroll
            for (int r = 0; r < 16; ++r) s[r] = exp2f(s[r]);
            if (needmask) {
#pragma unroll
                for (int gg = 0; gg < 4; ++gg)
#pragma unroll
                    for (int i = 0; i < 4; ++i) {
                        const int kcol = mi * 32 + gg * 8 + 4 * lh + i;
                        if (kcol < qr) s[gg * 4 + i] = 0.f;
                    }
            }
#pragma unroll
            for (int r = 0; r < 16; ++r) lsum += s[r];

            // ---- pack + register C->A transform (no LDS)
            u32 u[4][2];
#pragma unroll
            for (int R = 0; R < 4; ++R) {
                u[R][0] = pack_bf16_2(s[4 * R + 0], s[4 * R + 1]);
                u[R][1] = pack_bf16_2(s[4 * R + 2], s[4 * R + 3]);
            }
#pragma unroll
            for (int c1 = 0; c1 < 2; ++c1) {
                const u32 x0 = lh ? u[2 * c1][0] : u[2 * c1 + 1][0];
                const u32 x1 = lh ? u[2 * c1][1] : u[2 * c1 + 1][1];
                const u32 xs0 = (u32)__shfl_xor((int)x0, 32);
                const u32 xs1 = (u32)__shfl_xor((int)x1, 32);
                union { u32 w[4]; bf16x8 v; } pa;
                pa.w[0] = lh ? xs0 : u[2 * c1][0];
                pa.w[1] = lh ? xs1 : u[2 * c1][1];
                pa.w[2] = lh ? u[2 * c1 + 1][0] : xs0;
                pa.w[3] = lh ? u[2 * c1 + 1][1] : xs1;

                const int c2v = mi * 2 + c1;
                const u16* vtp = vfb + (size_t)(jt * 8 + c2v * 2) * 512;
                bf16x8 v0f = *(const bf16x8*)(vtp);
                bf16x8 v1f = *(const bf16x8*)(vtp + 512);
                o0 = __builtin_amdgcn_mfma_f32_32x32x16_bf16(pa.v, v0f, o0, 0, 0, 0);
                o1 = __builtin_amdgcn_mfma_f32_32x32x16_bf16(pa.v, v1f, o1, 0, 0, 0);
            }
        }
    }

    // ---- epilogue: unnormalized partials for (batch, band, chunk)
    const int slot = batch * NSLOT + qc;
    u16* ob = Op + (size_t)slot * OPSLOT;
#pragma unroll
    for (int r = 0; r < 16; ++r) {
        const int qrl = (r & 3) + 8 * (r >> 2) + 4 * lh;
        ob[(wid * 32 + qrl) * 64 + l31]      = f_to_bf16u(o0[r]);
        ob[(wid * 32 + qrl) * 64 + 32 + l31] = f_to_bf16u(o1[r]);
    }
    lsum += __shfl_xor(lsum, 32);
    if (lh == 0) Lp[(size_t)slot * 128 + wid * 32 + l31] = lsum;
}

// ---------------------------------------------------------------------------
// Combine NC(band)=32-band chunk-partials/row (pure sums) + output proj.
// ---------------------------------------------------------------------------
__global__ __launch_bounds__(256, 2)
void combine_proj_kernel(const u16* __restrict__ Op, const float* __restrict__ Lp,
                         const float* __restrict__ Wp, const float* __restrict__ bp,
                         float* __restrict__ out)
{
    const int tid  = threadIdx.x;
    const int wid  = tid >> 6;
    const int lane = tid & 63;
    const int ln   = lane & 15;
    const int qd   = lane >> 4;
    const int g    = blockIdx.x * 64 + wid * 16;
    const int row  = g + ln;

    const int batch = row >> 12;
    const int sr    = row & 4095;
    const int band  = sr >> 7;
    const int rl    = sr & 127;
    const int NC    = 32 - band;
    const int Cb    = 32 * band - ((band * (band - 1)) >> 1);
    const int sbase = batch * NSLOT + Cb;

    float acc0[8], acc1[8];
#pragma unroll
    for (int j = 0; j < 8; ++j) { acc0[j] = 0.f; acc1[j] = 0.f; }
    float l = 0.f;
    for (int s = 0; s < NC; ++s) {
        const int slot = sbase + s;
        const u16* op = Op + (size_t)slot * OPSLOT + rl * 64 + qd * 8;
        bf16x8 x0 = *(const bf16x8*)op;
        bf16x8 x1 = *(const bf16x8*)(op + 32);
#pragma unroll
        for (int j = 0; j < 8; ++j) { acc0[j] += (float)x0[j]; acc1[j] += (float)x1[j]; }
        l += Lp[(size_t)slot * 128 + rl];
    }
    float inv = 1.0f / l;
    bf16x8 afrag[2];
#pragma unroll
    for (int j = 0; j < 8; ++j) { afrag[0][j] = (__bf16)(acc0[j] * inv); afrag[1][j] = (__bf16)(acc1[j] * inv); }

    bf16x8 bfrag[4][2];
    float  bcol[4];
#pragma unroll
    for (int nb = 0; nb < 4; ++nb) {
        bcol[nb] = bp[nb * 16 + ln];
#pragma unroll
        for (int cc = 0; cc < 2; ++cc) {
            const float* src = Wp + (nb * 16 + ln) * 64 + cc * 32 + qd * 8;
            float4 f0 = *(const float4*)src;
            float4 f1 = *(const float4*)(src + 4);
            bf16x8 b;
            b[0] = (__bf16)f0.x; b[1] = (__bf16)f0.y; b[2] = (__bf16)f0.z; b[3] = (__bf16)f0.w;
            b[4] = (__bf16)f1.x; b[5] = (__bf16)f1.y; b[6] = (__bf16)f1.z; b[7] = (__bf16)f1.w;
            bfrag[nb][cc] = b;
        }
    }

    f32x4 acc[4];
#pragma unroll
    for (int nb = 0; nb < 4; ++nb) acc[nb] = (f32x4){0.f, 0.f, 0.f, 0.f};
#pragma unroll
    for (int cc = 0; cc < 2; ++cc)
#pragma unroll
        for (int nb = 0; nb < 4; ++nb)
            acc[nb] = __builtin_amdgcn_mfma_f32_16x16x32_bf16(afrag[cc], bfrag[nb][cc], acc[nb], 0, 0, 0);

#pragma unroll
    for (int nb = 0; nb < 4; ++nb)
#pragma unroll
        for (int r = 0; r < 4; ++r) {
            int rowo = g + qd * 4 + r;
            out[(size_t)rowo * 64 + nb * 16 + ln] = acc[nb][r] + bcol[nb];
        }
}

extern "C" void kernel_launch(void* const* d_in, const int* in_sizes, int n_in,
                              void* d_out, int out_size, void* d_ws, size_t ws_size,
                              hipStream_t stream) {
    const float* q  = (const float*)d_in[0];
    const float* k  = (const float*)d_in[1];
    const float* v  = (const float*)d_in[2];
    const float* Wq = (const float*)d_in[3];
    const float* bq = (const float*)d_in[4];
    const float* Wk = (const float*)d_in[5];
    const float* bk = (const float*)d_in[6];
    const float* Wv = (const float*)d_in[7];
    const float* bv = (const float*)d_in[8];
    const float* Wp = (const float*)d_in[9];
    const float* bp = (const float*)d_in[10];
    float* out = (float*)d_out;

    const size_t NTOK = (size_t)NBATCH * S_LEN * D_DIM;   // 1,048,576
    u16* Qf = (u16*)d_ws;                                  // 2 MB
    u16* Kf = Qf + NTOK;                                   // 2 MB
    u16* Vf = Kf + NTOK;                                   // 2 MB
    u16* Op = Vf + NTOK;                                   // 2112 slots * 16 KB = 34.6 MB
    float* Lp = (float*)(Op + (size_t)(NBATCH * NSLOT) * OPSLOT);   // 1.08 MB

    proj_qkv_kernel<<<dim3(256, 3), 256, 0, stream>>>(q, k, v, Wq, bq, Wk, bk, Wv, bv, Qf, Kf, Vf);
    flash_kernel<<<NBATCH * NSLOT, 256, 0, stream>>>(Qf, Kf, Vf, Op, Lp);
    combine_proj_kernel<<<256, 256, 0, stream>>>(Op, Lp, Wp, bp, out);
}

// Round 9
// 119.481 us; speedup vs baseline: 1.3385x; 1.3385x over previous
//
#include <hip/hip_runtime.h>
#include <hip/hip_bf16.h>

#define S_LEN 4096
#define D_DIM 64
#define NBATCH 4
#define NCHUNK 8
#define OPSLOT 8192   // u16 per slot: 128 rows * 64 cols
#define VSTR 88       // proj LDS stride: 176 B, 16B-aligned, 4-way-max banks

typedef unsigned short u16;
typedef unsigned int u32;
typedef __attribute__((ext_vector_type(8))) __bf16 bf16x8;
typedef __attribute__((ext_vector_type(4))) float f32x4;
typedef __attribute__((ext_vector_type(16))) float f32x16;

__device__ __forceinline__ u16 f_to_bf16u(float f) {
    union { float f; u32 u; } x; x.f = f;
    u32 r = x.u + 0x7fffu + ((x.u >> 16) & 1u);   // RNE; inputs finite
    return (u16)(r >> 16);
}

__device__ __forceinline__ u32 pack_bf16_2(float a, float b) {
    union { __hip_bfloat162 h; u32 u; } z;
    z.h = __float22bfloat162_rn(float2{a, b});
    return z.u;
}

// ---------------------------------------------------------------------------
// QKV projection. Q PRE-SCALED by 0.125*log2(e). ALL outputs fragment-major:
//   Q/K: Xf[(b*128 + t32)*4 + c2][lane][8], elem = X[t32*32+(lane&31)][c2*16+(lane>>5)*8+e]
//   V:   Vf[((b*64+jt)*4 + c2)*2 + dblk][lane][8],
//        elem = V[jt*64 + c2*16 + (lane>>5)*8 + e][dblk*32 + (lane&31)]
// Q/K now staged through LDS so the global stores are coalesced uint4
// (fixes v11's scalar scatter-store penalty).
// ---------------------------------------------------------------------------
__global__ __launch_bounds__(256, 2)
void proj_qkv_kernel(const float* __restrict__ q, const float* __restrict__ k,
                     const float* __restrict__ v,
                     const float* __restrict__ Wq, const float* __restrict__ bq,
                     const float* __restrict__ Wk, const float* __restrict__ bk,
                     const float* __restrict__ Wv, const float* __restrict__ bv,
                     u16* __restrict__ Qf, u16* __restrict__ Kf, u16* __restrict__ Vf)
{
    __shared__ __align__(16) u16 vt[64 * VSTR];   // 11,264 B

    const int p = blockIdx.y;
    const float* inp  = (p == 0) ? q  : (p == 1) ? k  : v;
    const float* W    = (p == 0) ? Wq : (p == 1) ? Wk : Wv;
    const float* bias = (p == 0) ? bq : (p == 1) ? bk : bv;
    const float scl   = (p == 0) ? 0.18033688011112042f : 1.0f;

    const int tid  = threadIdx.x;
    const int wid  = tid >> 6;
    const int lane = tid & 63;
    const int ln   = lane & 15;
    const int qd   = lane >> 4;
    const int row0 = blockIdx.x * 64;
    const int r0w  = row0 + wid * 16;

    bf16x8 afrag[2];
#pragma unroll
    for (int c = 0; c < 2; ++c) {
        const float* src = inp + (r0w + ln) * 64 + c * 32 + qd * 8;
        float4 f0 = *(const float4*)src;
        float4 f1 = *(const float4*)(src + 4);
        bf16x8 a;
        a[0] = (__bf16)f0.x; a[1] = (__bf16)f0.y; a[2] = (__bf16)f0.z; a[3] = (__bf16)f0.w;
        a[4] = (__bf16)f1.x; a[5] = (__bf16)f1.y; a[6] = (__bf16)f1.z; a[7] = (__bf16)f1.w;
        afrag[c] = a;
    }

    bf16x8 bfrag[4][2];
    float  bcol[4];
#pragma unroll
    for (int nb = 0; nb < 4; ++nb) {
        bcol[nb] = bias[nb * 16 + ln];
#pragma unroll
        for (int c = 0; c < 2; ++c) {
            const float* src = W + (nb * 16 + ln) * 64 + c * 32 + qd * 8;
            float4 f0 = *(const float4*)src;
            float4 f1 = *(const float4*)(src + 4);
            bf16x8 b;
            b[0] = (__bf16)f0.x; b[1] = (__bf16)f0.y; b[2] = (__bf16)f0.z; b[3] = (__bf16)f0.w;
            b[4] = (__bf16)f1.x; b[5] = (__bf16)f1.y; b[6] = (__bf16)f1.z; b[7] = (__bf16)f1.w;
            bfrag[nb][c] = b;
        }
    }

    f32x4 acc[4];
#pragma unroll
    for (int nb = 0; nb < 4; ++nb) acc[nb] = (f32x4){0.f, 0.f, 0.f, 0.f};
#pragma unroll
    for (int c = 0; c < 2; ++c)
#pragma unroll
        for (int nb = 0; nb < 4; ++nb)
            acc[nb] = __builtin_amdgcn_mfma_f32_16x16x32_bf16(afrag[c], bfrag[nb][c], acc[nb], 0, 0, 0);

    // stage result tile (64 rows x 64 cols) to LDS
#pragma unroll
    for (int nb = 0; nb < 4; ++nb)
#pragma unroll
        for (int r = 0; r < 4; ++r)
            vt[(wid * 16 + qd * 4 + r) * VSTR + nb * 16 + ln] = f_to_bf16u((acc[nb][r] + bcol[nb]) * scl);
    __syncthreads();

    const int bb  = row0 >> 12;
    const int ri0 = row0 & 4095;

    if (p < 2) {
        // gather fragment vectors + coalesced uint4 stores (1 KB per 64 threads)
        u16* dst = (p == 0) ? Qf : Kf;
#pragma unroll
        for (int half = 0; half < 2; ++half) {           // half == local tile32
            const int vid = half * 256 + tid;
            const int c2  = (vid >> 6) & 3;
            const int ln2 = vid & 63;
            const int rl  = half * 32 + (ln2 & 31);
            const int col = c2 * 16 + (ln2 >> 5) * 8;
            uint4 vvec = *(const uint4*)(&vt[rl * VSTR + col]);
            const int gt32 = (ri0 >> 5) + half;
            *(uint4*)(dst + (((size_t)(bb * 128 + gt32) * 4 + c2) * 512 + ln2 * 8)) = vvec;
        }
    } else {
        // fragment-major V (transposed gather, coalesced uint4 stores)
        const int c2w  = tid >> 6;
        const int lw   = tid & 63;
        const int lhw  = lw >> 5;
        const int l31w = lw & 31;
        const int jt   = ri0 >> 6;
        u16* vdst = Vf + ((size_t)((bb * 64 + jt) * 4 + c2w) * 2) * 512 + lw * 8;
        __align__(16) u16 t8[8];
#pragma unroll
        for (int dblk = 0; dblk < 2; ++dblk) {
#pragma unroll
            for (int e = 0; e < 8; ++e)
                t8[e] = vt[(c2w * 16 + lhw * 8 + e) * VSTR + dblk * 32 + l31w];
            *(uint4*)(vdst + dblk * 512) = *(const uint4*)t8;
        }
    }
}

// ---------------------------------------------------------------------------
// Flash v13 = v8's proven grid/mapping (1024 blocks, 4/CU, NCHUNK=8,
// balanced band permutation {h,15-h,16+h,31-h}) + v11's verified interior
// (no LDS, no barriers, fragment-major coalesced dwordx4 loads; K/V L2-
// resident: 1 MB/XCD working set, FETCH ~6 MB at this grid size per v10).
// v12 lesson: do NOT exceed ~4 blocks/CU (L2 thrash + write amplification).
// ---------------------------------------------------------------------------
__global__ __launch_bounds__(256, 4)
void flash_kernel(const u16* __restrict__ Qf, const u16* __restrict__ Kf,
                  const u16* __restrict__ Vf, u16* __restrict__ Op,
                  float* __restrict__ Lp)
{
    const int tid  = threadIdx.x;
    const int wid  = tid >> 6;
    const int lane = tid & 63;
    const int l31  = lane & 31;
    const int lh   = lane >> 5;

    const int bid   = blockIdx.x;
    const int batch = bid & 3;            // XCD locality
    const int c     = (bid >> 2) & 7;     // j-chunk 0..7
    const int g     = bid >> 5;           // 0..31
    const int h     = g & 7;
    const int qq    = g >> 3;
    const int band  = (qq == 0) ? h : (qq == 1) ? (15 - h) : (qq == 2) ? (16 + h) : (31 - h);

    const int i0w = band * 128 + wid * 32;
    const int jt0 = 2 * band + ((c - 2 * band) & 7);

    // Q fragments: one coalesced dwordx4 per c2
    bf16x8 qf[4];
    {
        const u16* qb = Qf + ((size_t)((batch * 128 + band * 4 + wid) * 4)) * 512 + lane * 8;
#pragma unroll
        for (int c2 = 0; c2 < 4; ++c2)
            qf[c2] = *(const bf16x8*)(qb + c2 * 512);
    }

    const u16* kfb = Kf + ((size_t)batch * 128 * 4) * 512 + lane * 8;
    const u16* vfb = Vf + ((size_t)batch * 64 * 8) * 512 + lane * 8;

    f32x16 o0, o1;
#pragma unroll
    for (int r = 0; r < 16; ++r) { o0[r] = 0.f; o1[r] = 0.f; }
    float lsum = 0.f;

#pragma unroll 1
    for (int jt = jt0; jt < 64; jt += NCHUNK) {
        const int j0 = jt * 64;
        const bool needmask = (j0 < i0w + 32);
        const int qr = i0w + l31 - j0;    // local qrow bound

#pragma unroll
        for (int mi = 0; mi < 2; ++mi) {
            const u16* kt = kfb + (size_t)(jt * 2 + mi) * 2048;

            // ---- S^T (kcols mi*32..mi*32+31)
            f32x16 s;
#pragma unroll
            for (int r = 0; r < 16; ++r) s[r] = 0.f;
#pragma unroll
            for (int c2 = 0; c2 < 4; ++c2) {
                bf16x8 a = *(const bf16x8*)(kt + c2 * 512);
                s = __builtin_amdgcn_mfma_f32_32x32x16_bf16(a, qf[c2], s, 0, 0, 0);
            }

            // ---- exp2 (Q pre-scaled) + mask; per-lane l partial
#pragma unroll
            for (int r = 0; r < 16; ++r) s[r] = exp2f(s[r]);
            if (needmask) {
#pragma unroll
                for (int gg = 0; gg < 4; ++gg)
#pragma unroll
                    for (int i = 0; i < 4; ++i) {
                        const int kcol = mi * 32 + gg * 8 + 4 * lh + i;
                        if (kcol < qr) s[gg * 4 + i] = 0.f;
                    }
            }
#pragma unroll
            for (int r = 0; r < 16; ++r) lsum += s[r];

            // ---- pack + register C->A transform (no LDS)
            u32 u[4][2];
#pragma unroll
            for (int R = 0; R < 4; ++R) {
                u[R][0] = pack_bf16_2(s[4 * R + 0], s[4 * R + 1]);
                u[R][1] = pack_bf16_2(s[4 * R + 2], s[4 * R + 3]);
            }
#pragma unroll
            for (int c1 = 0; c1 < 2; ++c1) {
                const u32 x0 = lh ? u[2 * c1][0] : u[2 * c1 + 1][0];
                const u32 x1 = lh ? u[2 * c1][1] : u[2 * c1 + 1][1];
                const u32 xs0 = (u32)__shfl_xor((int)x0, 32);
                const u32 xs1 = (u32)__shfl_xor((int)x1, 32);
                union { u32 w[4]; bf16x8 v; } pa;
                pa.w[0] = lh ? xs0 : u[2 * c1][0];
                pa.w[1] = lh ? xs1 : u[2 * c1][1];
                pa.w[2] = lh ? u[2 * c1 + 1][0] : xs0;
                pa.w[3] = lh ? u[2 * c1 + 1][1] : xs1;

                const int c2v = mi * 2 + c1;
                const u16* vtp = vfb + (size_t)(jt * 8 + c2v * 2) * 512;
                bf16x8 v0f = *(const bf16x8*)(vtp);
                bf16x8 v1f = *(const bf16x8*)(vtp + 512);
                o0 = __builtin_amdgcn_mfma_f32_32x32x16_bf16(pa.v, v0f, o0, 0, 0, 0);
                o1 = __builtin_amdgcn_mfma_f32_32x32x16_bf16(pa.v, v1f, o1, 0, 0, 0);
            }
        }
    }

    // ---- epilogue: unnormalized partials for (batch, band, chunk)
    const int slot = (batch * 32 + band) * NCHUNK + c;
    u16* ob = Op + (size_t)slot * OPSLOT;
#pragma unroll
    for (int r = 0; r < 16; ++r) {
        const int qrl = (r & 3) + 8 * (r >> 2) + 4 * lh;
        ob[(wid * 32 + qrl) * 64 + l31]      = f_to_bf16u(o0[r]);
        ob[(wid * 32 + qrl) * 64 + 32 + l31] = f_to_bf16u(o1[r]);
    }
    lsum += __shfl_xor(lsum, 32);
    if (lh == 0) Lp[(size_t)slot * 128 + wid * 32 + l31] = lsum;
}

// ---------------------------------------------------------------------------
// Combine 8 chunk-partials/row (pure sums, max-free) + output projection.
// ---------------------------------------------------------------------------
__global__ __launch_bounds__(256, 2)
void combine_proj_kernel(const u16* __restrict__ Op, const float* __restrict__ Lp,
                         const float* __restrict__ Wp, const float* __restrict__ bp,
                         float* __restrict__ out)
{
    const int tid  = threadIdx.x;
    const int wid  = tid >> 6;
    const int lane = tid & 63;
    const int ln   = lane & 15;
    const int qd   = lane >> 4;
    const int g    = blockIdx.x * 64 + wid * 16;
    const int row  = g + ln;

    const int batch = row >> 12;
    const int sr    = row & 4095;
    const int band  = sr >> 7;
    const int rl    = sr & 127;
    const int sbase = (batch * 32 + band) * NCHUNK;

    float acc0[8], acc1[8];
#pragma unroll
    for (int j = 0; j < 8; ++j) { acc0[j] = 0.f; acc1[j] = 0.f; }
    float l = 0.f;
#pragma unroll
    for (int s = 0; s < NCHUNK; ++s) {
        const int slot = sbase + s;
        const u16* op = Op + (size_t)slot * OPSLOT + rl * 64 + qd * 8;
        bf16x8 x0 = *(const bf16x8*)op;
        bf16x8 x1 = *(const bf16x8*)(op + 32);
#pragma unroll
        for (int j = 0; j < 8; ++j) { acc0[j] += (float)x0[j]; acc1[j] += (float)x1[j]; }
        l += Lp[(size_t)slot * 128 + rl];
    }
    float inv = 1.0f / l;
    bf16x8 afrag[2];
#pragma unroll
    for (int j = 0; j < 8; ++j) { afrag[0][j] = (__bf16)(acc0[j] * inv); afrag[1][j] = (__bf16)(acc1[j] * inv); }

    bf16x8 bfrag[4][2];
    float  bcol[4];
#pragma unroll
    for (int nb = 0; nb < 4; ++nb) {
        bcol[nb] = bp[nb * 16 + ln];
#pragma unroll
        for (int cc = 0; cc < 2; ++cc) {
            const float* src = Wp + (nb * 16 + ln) * 64 + cc * 32 + qd * 8;
            float4 f0 = *(const float4*)src;
            float4 f1 = *(const float4*)(src + 4);
            bf16x8 b;
            b[0] = (__bf16)f0.x; b[1] = (__bf16)f0.y; b[2] = (__bf16)f0.z; b[3] = (__bf16)f0.w;
            b[4] = (__bf16)f1.x; b[5] = (__bf16)f1.y; b[6] = (__bf16)f1.z; b[7] = (__bf16)f1.w;
            bfrag[nb][cc] = b;
        }
    }

    f32x4 acc[4];
#pragma unroll
    for (int nb = 0; nb < 4; ++nb) acc[nb] = (f32x4){0.f, 0.f, 0.f, 0.f};
#pragma unroll
    for (int cc = 0; cc < 2; ++cc)
#pragma unroll
        for (int nb = 0; nb < 4; ++nb)
            acc[nb] = __builtin_amdgcn_mfma_f32_16x16x32_bf16(afrag[cc], bfrag[nb][cc], acc[nb], 0, 0, 0);

#pragma unroll
    for (int nb = 0; nb < 4; ++nb)
#pragma unroll
        for (int r = 0; r < 4; ++r) {
            int rowo = g + qd * 4 + r;
            out[(size_t)rowo * 64 + nb * 16 + ln] = acc[nb][r] + bcol[nb];
        }
}

extern "C" void kernel_launch(void* const* d_in, const int* in_sizes, int n_in,
                              void* d_out, int out_size, void* d_ws, size_t ws_size,
                              hipStream_t stream) {
    const float* q  = (const float*)d_in[0];
    const float* k  = (const float*)d_in[1];
    const float* v  = (const float*)d_in[2];
    const float* Wq = (const float*)d_in[3];
    const float* bq = (const float*)d_in[4];
    const float* Wk = (const float*)d_in[5];
    const float* bk = (const float*)d_in[6];
    const float* Wv = (const float*)d_in[7];
    const float* bv = (const float*)d_in[8];
    const float* Wp = (const float*)d_in[9];
    const float* bp = (const float*)d_in[10];
    float* out = (float*)d_out;

    const size_t NTOK = (size_t)NBATCH * S_LEN * D_DIM;   // 1,048,576
    u16* Qf = (u16*)d_ws;                                  // 2 MB
    u16* Kf = Qf + NTOK;                                   // 2 MB
    u16* Vf = Kf + NTOK;                                   // 2 MB
    u16* Op = Vf + NTOK;                                   // 1024 slots * 16 KB = 16 MB
    float* Lp = (float*)(Op + (size_t)1024 * OPSLOT);      // 512 KB

    proj_qkv_kernel<<<dim3(256, 3), 256, 0, stream>>>(q, k, v, Wq, bq, Wk, bk, Wv, bv, Qf, Kf, Vf);
    flash_kernel<<<1024, 256, 0, stream>>>(Qf, Kf, Vf, Op, Lp);
    combine_proj_kernel<<<256, 256, 0, stream>>>(Op, Lp, Wp, bp, out);
}